// Round 1
// baseline (260.486 us; speedup 1.0000x reference)
//
#include <hip/hip_runtime.h>
#include <hip/hip_bf16.h>
#include <stdint.h>
#include <math.h>

#define SEQ 4096
#define DIM 1024
#define NHEADS 16
#define DHEAD 64
#define INNER 1024

typedef __hip_bfloat16 bf16;
typedef __attribute__((ext_vector_type(8))) short short8;
typedef __attribute__((ext_vector_type(4))) float floatx4;

// async global->LDS, 16B per lane; lane i's 16B lands at dest + i*16.
__device__ __forceinline__ void gll16(const bf16* g, bf16* l) {
    __builtin_amdgcn_global_load_lds(
        (const __attribute__((address_space(1))) unsigned int*)g,
        (__attribute__((address_space(3))) unsigned int*)l,
        16, 0, 0);
}

__device__ __forceinline__ unsigned short f2bf_bits(float f) {
    bf16 h = __float2bfloat16(f);
    return *reinterpret_cast<unsigned short*>(&h);
}

__device__ __forceinline__ uint2 pack4bf(float a, float b, float c, float d) {
    __hip_bfloat162 lo = __float22bfloat162_rn(float2{a, b});
    __hip_bfloat162 hi = __float22bfloat162_rn(float2{c, d});
    uint2 r;
    r.x = *reinterpret_cast<unsigned*>(&lo);
    r.y = *reinterpret_cast<unsigned*>(&hi);
    return r;
}

// ---------------- prep: z=0..3 weight transpose+convert; z=4 x convert ----------------
__global__ __launch_bounds__(256) void prep_kernel(
        const float* __restrict__ x, const float* __restrict__ W0,
        const float* __restrict__ W1, const float* __restrict__ W2,
        const float* __restrict__ W3, bf16* __restrict__ xb,
        bf16* __restrict__ T0, bf16* __restrict__ T1,
        bf16* __restrict__ T2, bf16* __restrict__ T3) {
    const int tid = threadIdx.x + threadIdx.y * blockDim.x;  // 0..255
    if (blockIdx.z == 4) {
        // convert x: block (bx,by) -> chunk (by*32+bx) of 4096 floats
        int chunk = blockIdx.y * 32 + blockIdx.x;
        int base = chunk * 4096 + tid * 4;
        #pragma unroll
        for (int r = 0; r < 4; r++) {
            int i = base + r * 1024;
            float4 f = *reinterpret_cast<const float4*>(x + i);
            unsigned long long p = (unsigned long long)f2bf_bits(f.x)
                                 | ((unsigned long long)f2bf_bits(f.y) << 16)
                                 | ((unsigned long long)f2bf_bits(f.z) << 32)
                                 | ((unsigned long long)f2bf_bits(f.w) << 48);
            *reinterpret_cast<unsigned long long*>(xb + i) = p;
        }
        return;
    }
    const float* W; bf16* T;
    switch (blockIdx.z) {
        case 0:  W = W0; T = T0; break;
        case 1:  W = W1; T = T1; break;
        case 2:  W = W2; T = T2; break;
        default: W = W3; T = T3; break;
    }
    __shared__ float tile[32][33];
    int k0 = blockIdx.x * 32, n0 = blockIdx.y * 32;
    int tx = threadIdx.x, ty = threadIdx.y;
    #pragma unroll
    for (int i = 0; i < 4; i++)
        tile[ty + 8 * i][tx] = W[(size_t)(k0 + ty + 8 * i) * 1024 + n0 + tx];
    __syncthreads();
    #pragma unroll
    for (int i = 0; i < 4; i++)
        T[(size_t)(n0 + ty + 8 * i) * 1024 + k0 + tx] = __float2bfloat16(tile[tx][ty + 8 * i]);
}

// ---------------- 128x128 bf16 MFMA GEMM tile body (K=1024), m97-style ----------------
__device__ __forceinline__ void gemm128_body(const bf16* __restrict__ A,
                                             const bf16* __restrict__ Bt,
                                             int m0, int n0, floatx4 acc[4][4]) {
    __shared__ __align__(16) bf16 As[8192];
    __shared__ __align__(16) bf16 Bs[8192];
    const int tid = threadIdx.x;
    const int wave = tid >> 6;
    const int lane = tid & 63;
    const int l15 = lane & 15;
    const int quad = lane >> 4;

    #pragma unroll
    for (int i = 0; i < 4; i++)
        #pragma unroll
        for (int j = 0; j < 4; j++)
            acc[i][j] = (floatx4){0.f, 0.f, 0.f, 0.f};

    for (int k0 = 0; k0 < 1024; k0 += 64) {
        __syncthreads();
        #pragma unroll
        for (int j = 0; j < 4; j++) {
            int t = wave * 4 + j;
            int row = (t >> 1) * 16 + l15;
            int kb = (t & 1) * 32 + quad * 8;
            gll16(A + (size_t)(m0 + row) * 1024 + k0 + kb, &As[t * 512]);
            gll16(Bt + (size_t)(n0 + row) * 1024 + k0 + kb, &Bs[t * 512]);
        }
        __syncthreads();
        #pragma unroll
        for (int ks = 0; ks < 2; ks++) {
            short8 af[4], bfr[4];
            #pragma unroll
            for (int i = 0; i < 4; i++)
                af[i] = *reinterpret_cast<const short8*>(
                    &As[((((wave >> 1) * 4 + i) * 2 + ks) * 512) + lane * 8]);
            #pragma unroll
            for (int j = 0; j < 4; j++)
                bfr[j] = *reinterpret_cast<const short8*>(
                    &Bs[((((wave & 1) * 4 + j) * 2 + ks) * 512) + lane * 8]);
            #pragma unroll
            for (int i = 0; i < 4; i++)
                #pragma unroll
                for (int j = 0; j < 4; j++)
                    acc[i][j] = __builtin_amdgcn_mfma_f32_16x16x32_bf16(af[i], bfr[j], acc[i][j], 0, 0, 0);
        }
    }
}

// ---------------- QKV projection ----------------
// z=0: Q (scaled by beta*log2e so attention uses raw v_exp_f32; [h][seq][64])
// z=1: K ([h][seq][64])
// z=2: V written TRANSPOSED directly: Vt[h][d][seq] (b64 packed stores).
__global__ __launch_bounds__(256) void qkv_gemm_kernel(
        const bf16* __restrict__ xb,
        const bf16* __restrict__ Wqt, const bf16* __restrict__ Wkt, const bf16* __restrict__ Wvt,
        bf16* __restrict__ Qh, bf16* __restrict__ Kh, bf16* __restrict__ Vt) {
    const bf16* Bt;
    if (blockIdx.z == 0)      Bt = Wqt;
    else if (blockIdx.z == 1) Bt = Wkt;
    else                      Bt = Wvt;
    int n0 = blockIdx.x * 128, m0 = blockIdx.y * 128;
    floatx4 acc[4][4];
    gemm128_body(xb, Bt, m0, n0, acc);

    const int tid = threadIdx.x, wave = tid >> 6, lane = tid & 63;
    const int l15 = lane & 15, quad = lane >> 4;
    const int wm = (wave >> 1) * 64, wn = (wave & 1) * 64;
    if (blockIdx.z == 2) {
        #pragma unroll
        for (int i = 0; i < 4; i++)
            #pragma unroll
            for (int j = 0; j < 4; j++) {
                int col = n0 + wn + j * 16 + l15;
                int h = col >> 6, d = col & 63;
                int row0 = m0 + wm + i * 16 + quad * 4;
                uint2 v = pack4bf(acc[i][j][0], acc[i][j][1], acc[i][j][2], acc[i][j][3]);
                *reinterpret_cast<uint2*>(Vt + ((size_t)h * DHEAD + d) * SEQ + row0) = v;
            }
    } else {
        bf16* O = (blockIdx.z == 0) ? Qh : Kh;
        float scale = (blockIdx.z == 0) ? 0.125f * 1.4426950408889634f : 1.0f;
        #pragma unroll
        for (int i = 0; i < 4; i++)
            #pragma unroll
            for (int j = 0; j < 4; j++) {
                int col = n0 + wn + j * 16 + l15;
                int h = col >> 6, d = col & 63;
                #pragma unroll
                for (int r = 0; r < 4; r++) {
                    int row = m0 + wm + i * 16 + quad * 4 + r;
                    O[((size_t)h * SEQ + row) * DHEAD + d] = __float2bfloat16(acc[i][j][r] * scale);
                }
            }
    }
}

// ---------------- output projection: out = Oa @ Wo + bo (fp32 out) ----------------
__global__ __launch_bounds__(256) void out_gemm_kernel(
        const bf16* __restrict__ Oa, const bf16* __restrict__ Wot,
        const float* __restrict__ bo, float* __restrict__ out) {
    int n0 = blockIdx.x * 128, m0 = blockIdx.y * 128;
    floatx4 acc[4][4];
    gemm128_body(Oa, Wot, m0, n0, acc);

    const int tid = threadIdx.x, wave = tid >> 6, lane = tid & 63;
    const int l15 = lane & 15, quad = lane >> 4;
    const int wm = (wave >> 1) * 64, wn = (wave & 1) * 64;
    #pragma unroll
    for (int i = 0; i < 4; i++)
        #pragma unroll
        for (int j = 0; j < 4; j++) {
            int col = n0 + wn + j * 16 + l15;
            float b = bo[col];
            #pragma unroll
            for (int r = 0; r < 4; r++) {
                int row = m0 + wm + i * 16 + quad * 4 + r;
                out[(size_t)row * DIM + col] = acc[i][j][r] + b;
            }
        }
}

// ---------------- causal flash attention (R9: double-buffered BK=64 pipeline) ----------------
// Block = 4 waves x 16 q-rows. Sᵀ = K·Qᵀ (per-lane softmax denom; Q pre-scaled
// by beta*log2e => p = v_exp_f32(s) via __builtin_amdgcn_exp2f — do NOT use
// exp2f (precise libcall, +15 µs measured R8) or carry a per-score mul).
// R9 restructure (theory: R4's 2-barrier-per-tile loop exposed the full
// global_load_lds drain to all waves -> MfmaUtil 15%, latency-bound):
//   * BK=64, K/V double-buffered: stage(kt+1) issued BEFORE compute(kt);
//     ONE __syncthreads per tile (its vmcnt(0) drain lands after ~400cy of
//     compute has hidden the L2 latency).
//   * LDS 40 KB -> 4 blocks/CU (16 waves/CU, up from 12).
//   * All 1024 blocks co-resident (one round) => heavy-first no longer
//     balances. Co-resident ids differ by 256 => ranks {r,r+16,r+32,r+48};
//     qt map below makes each such quadruple sum to 126 tiles (bijective).
//   * head = id&15 keeps 2 heads/XCD L2 pinning (FETCH 12 MB, R4).
//   * T5 setprio(1) around MFMA clusters (4 blocks/CU at different phases
//     = wave role diversity regime where it pays).
// DO NOT: drop staging (R6), V in regs (R7 spill).
__global__ __launch_bounds__(256, 4) void attention_kernel(
        const bf16* __restrict__ Qh, const bf16* __restrict__ Kh,
        const bf16* __restrict__ Vt, bf16* __restrict__ Oa) {
    __shared__ __align__(16) bf16 Ksh[2][4096];  // 2 x 8 KB: frag t = keygrp*2 + khalf
    __shared__ __align__(16) bf16 Vsh[2][4096];  // 2 x 8 KB: frag t = dgrp*2 + kseg
    __shared__ __align__(16) bf16 Ps[4][1024];   // 2 KB/wave: frag s = key/32
    const int tid = threadIdx.x, wave = tid >> 6, lane = tid & 63;
    const int l15 = lane & 15, quad = lane >> 4;
    const int id = blockIdx.x;
    const int head = id & 15;                    // XCD id&7 serves heads {h, h+8}
    const int rk = id >> 4;                      // 0..63
    const int r0 = rk & 15, bsel = (rk >> 4) & 1, c2 = rk >> 5;
    const int qt = bsel ? (2 * r0 + c2) : (63 - 2 * r0 - c2);  // balanced co-resident sets
    const int qw = qt * 64 + wave * 16;          // wave's q-row base
    const size_t hoff = (size_t)head * SEQ * DHEAD;
    const bf16* Qb = Qh + hoff;
    const bf16* Kb = Kh + hoff;
    const bf16* Vb = Vt + hoff;                  // [d][seq]

    // Q as B-operand fragments: lane n = l15 -> q-row qw+l15, k along d
    short8 bq[2];
    #pragma unroll
    for (int s = 0; s < 2; s++)
        bq[s] = *reinterpret_cast<const short8*>(
            Qb + (size_t)(qw + l15) * DHEAD + s * 32 + quad * 8);

    floatx4 acc_o[4];                            // Oᵀ: d = c*16+quad*4+r, q = l15
    #pragma unroll
    for (int c = 0; c < 4; c++) acc_o[c] = (floatx4){0.f, 0.f, 0.f, 0.f};
    float l_part = 0.f;                          // per-lane softmax denom partial

    // per-wave stage of one 64-key K tile + V tile into buffer `buf`
    auto stage = [&](int buf, int kbase) {
        #pragma unroll
        for (int j = 0; j < 2; j++) {
            int t = wave * 2 + j;                // t = 0..7 across 4 waves
            gll16(Kb + (size_t)(kbase + (t >> 1) * 16 + l15) * DHEAD + (t & 1) * 32 + quad * 8,
                  &Ksh[buf][t * 512]);
            gll16(Vb + (size_t)((t >> 1) * 16 + l15) * SEQ + kbase + (t & 1) * 32 + quad * 8,
                  &Vsh[buf][t * 512]);
        }
    };

    const int ntiles = qt + 1;                   // BK=64: keys 0..qt*64+63 exactly
    stage(0, 0);
    __syncthreads();                             // vmcnt(0) drain + tile 0 visible
    int cur = 0;
    for (int kt = 0; kt < ntiles; kt++) {
        const int kbase = kt * 64;
        if (kt + 1 < ntiles) stage(cur ^ 1, (kt + 1) * 64);  // async prefetch

        // Sᵀ = K·Qᵀ: linear conflict-free b128 LDS reads
        floatx4 st[4];
        #pragma unroll
        for (int c = 0; c < 4; c++) st[c] = (floatx4){0.f, 0.f, 0.f, 0.f};
        __builtin_amdgcn_s_setprio(1);
        #pragma unroll
        for (int c = 0; c < 4; c++) {
            short8 ak0 = *reinterpret_cast<const short8*>(&Ksh[cur][(c * 2 + 0) * 512 + lane * 8]);
            short8 ak1 = *reinterpret_cast<const short8*>(&Ksh[cur][(c * 2 + 1) * 512 + lane * 8]);
            st[c] = __builtin_amdgcn_mfma_f32_16x16x32_bf16(ak0, bq[0], st[c], 0, 0, 0);
            st[c] = __builtin_amdgcn_mfma_f32_16x16x32_bf16(ak1, bq[1], st[c], 0, 0, 0);
        }
        __builtin_amdgcn_s_setprio(0);
        // causal mask: key = kbase + c*16 + quad*4 + r, q = qw + l15
        if (kbase + 63 > qw) {                   // wave-uniform
            int base0 = kbase + quad * 4 - qw - l15;
            #pragma unroll
            for (int c = 0; c < 4; c++) {
                int base = base0 + c * 16;
                #pragma unroll
                for (int r = 0; r < 4; r++)
                    if (base + r > 0) st[c][r] = -1e30f;
            }
        }
        // p = 2^s: raw v_exp_f32 (masked -> 2^-1e30 = 0); per-lane denom; pack Ps
        #pragma unroll
        for (int c = 0; c < 4; c++) {
            float p0 = __builtin_amdgcn_exp2f(st[c][0]);
            float p1 = __builtin_amdgcn_exp2f(st[c][1]);
            float p2 = __builtin_amdgcn_exp2f(st[c][2]);
            float p3 = __builtin_amdgcn_exp2f(st[c][3]);
            l_part += (p0 + p1) + (p2 + p3);
            int elem = (c >> 1) * 512
                     + (l15 + 16 * ((c & 1) * 2 + (quad >> 1))) * 8 + (quad & 1) * 4;
            *reinterpret_cast<uint2*>(&Ps[wave][elem]) = pack4bf(p0, p1, p2, p3);
        }
        // Oᵀ += Vᵀ·Pᵀ: A-frag = Vᵀ d-rows, B-frag = Pᵀ (both linear b128)
        __builtin_amdgcn_s_setprio(1);
        #pragma unroll
        for (int s = 0; s < 2; s++) {
            short8 bp = *reinterpret_cast<const short8*>(&Ps[wave][s * 512 + lane * 8]);
            #pragma unroll
            for (int c = 0; c < 4; c++) {
                short8 av = *reinterpret_cast<const short8*>(&Vsh[cur][(c * 2 + s) * 512 + lane * 8]);
                acc_o[c] = __builtin_amdgcn_mfma_f32_16x16x32_bf16(av, bp, acc_o[c], 0, 0, 0);
            }
        }
        __builtin_amdgcn_s_setprio(0);

        __syncthreads();                         // readers done + prefetch drained
        cur ^= 1;
    }
    // denom: sum the 4 quad-lanes holding this q-row
    float l = l_part;
    l += __shfl_xor(l, 16, 64);
    l += __shfl_xor(l, 32, 64);
    float rcp = 1.0f / l;
    // write O row-major [SEQ][INNER]: col q = qw+l15, rows d = c*16+quad*4+r
    const int q = qw + l15;
    #pragma unroll
    for (int c = 0; c < 4; c++) {
        uint2 v = pack4bf(acc_o[c][0] * rcp, acc_o[c][1] * rcp,
                          acc_o[c][2] * rcp, acc_o[c][3] * rcp);
        *reinterpret_cast<uint2*>(Oa + (size_t)q * INNER + head * DHEAD + c * 16 + quad * 4) = v;
    }
}

extern "C" void kernel_launch(void* const* d_in, const int* in_sizes, int n_in,
                              void* d_out, int out_size, void* d_ws, size_t ws_size,
                              hipStream_t stream) {
    const float* x  = (const float*)d_in[0];
    const float* Wq = (const float*)d_in[1];
    const float* Wk = (const float*)d_in[2];
    const float* Wv = (const float*)d_in[3];
    const float* Wo = (const float*)d_in[4];
    const float* bo = (const float*)d_in[5];
    float* out = (float*)d_out;

    char* ws = (char*)d_ws;
    size_t off = 0;
    bf16* xb  = (bf16*)(ws + off); off += (size_t)SEQ * DIM * 2;
    bf16* Wqt = (bf16*)(ws + off); off += (size_t)DIM * INNER * 2;
    bf16* Wkt = (bf16*)(ws + off); off += (size_t)DIM * INNER * 2;
    bf16* Wvt = (bf16*)(ws + off); off += (size_t)DIM * INNER * 2;
    bf16* Wot = (bf16*)(ws + off); off += (size_t)INNER * DIM * 2;
    bf16* Qh  = (bf16*)(ws + off); off += (size_t)NHEADS * SEQ * DHEAD * 2;
    bf16* Kh  = (bf16*)(ws + off); off += (size_t)NHEADS * SEQ * DHEAD * 2;
    bf16* Vtr = (bf16*)(ws + off); off += (size_t)NHEADS * DHEAD * SEQ * 2;
    bf16* Oa  = (bf16*)(ws + off); off += (size_t)SEQ * INNER * 2;  // ~48 MB total

    prep_kernel<<<dim3(32, 32, 5), dim3(32, 8), 0, stream>>>(x, Wq, Wk, Wv, Wo,
                                                             xb, Wqt, Wkt, Wvt, Wot);
    qkv_gemm_kernel<<<dim3(8, 32, 3), 256, 0, stream>>>(xb, Wqt, Wkt, Wvt, Qh, Kh, Vtr);
    attention_kernel<<<1024, 256, 0, stream>>>(Qh, Kh, Vtr, Oa);
    out_gemm_kernel<<<dim3(8, 32), 256, 0, stream>>>(Oa, Wot, bo, out);
}